// Round 1
// baseline (2294.118 us; speedup 1.0000x reference)
//
#include <hip/hip_runtime.h>
#include <cstddef>
#include <cstdint>

#define B_  2
#define N_  2048
#define M_  8192
#define C1_ 256
#define C_  128
#define K_  16
#define CS_ 16

// 1/sqrt(1+1e-5)
#define BNINV 0.9999950000374997f

// ---------------------------------------------------------------------------
// f_t[b,n,c] = relu(bn1(tu_lin1_w @ feature))   (stored point-major for coalesced gather)
extern "C" __global__ __launch_bounds__(C_) void k_f(
    const float* __restrict__ feature, const float* __restrict__ w,
    const float* __restrict__ g, const float* __restrict__ bb,
    float* __restrict__ f_t)
{
    int bn = blockIdx.x;            // b*N_ + n
    int b  = bn / N_;
    int n  = bn - b * N_;
    int c  = threadIdx.x;
    const float* fp = feature + (size_t)b * C1_ * N_ + n;
    const float* wr = w + (size_t)c * C1_;
    float acc = 0.f;
#pragma unroll 8
    for (int j = 0; j < C1_; ++j)
        acc = fmaf(wr[j], fp[(size_t)j * N_], acc);
    f_t[(size_t)bn * C_ + c] = fmaxf(fmaf(acc, g[c] * BNINV, bb[c]), 0.f);
}

// ---------------------------------------------------------------------------
// three_nn: per target point, 3 nearest source points + interp weights
extern "C" __global__ __launch_bounds__(64) void k_three_nn(
    const float* __restrict__ xyz, const float* __restrict__ txyz,
    int* __restrict__ idx3, float* __restrict__ w3)
{
    int t = blockIdx.x * 64 + threadIdx.x;      // 0..B*M-1 (b uniform per block)
    int b = t / M_;
    __shared__ float sx[64], sy[64], sz[64];
    const float* src = xyz + (size_t)b * N_ * 3;
    float qx = txyz[(size_t)t*3+0], qy = txyz[(size_t)t*3+1], qz = txyz[(size_t)t*3+2];
    float d0 = 3e38f, d1 = 3e38f, d2 = 3e38f;
    int   i0 = 0, i1 = 0, i2 = 0;
    for (int cb = 0; cb < N_; cb += 64) {
        int j = cb + threadIdx.x;
        sx[threadIdx.x] = src[j*3+0];
        sy[threadIdx.x] = src[j*3+1];
        sz[threadIdx.x] = src[j*3+2];
        __syncthreads();
#pragma unroll 4
        for (int jj = 0; jj < 64; ++jj) {
            float dx = sx[jj]-qx, dy = sy[jj]-qy, dz = sz[jj]-qz;
            // match reference arithmetic exactly: (dx*dx + dy*dy) + dz*dz, no FMA
            float d = __fadd_rn(__fadd_rn(__fmul_rn(dx,dx), __fmul_rn(dy,dy)), __fmul_rn(dz,dz));
            if (d < d2) {
                int idx = cb + jj;
                if (d < d1) {
                    d2 = d1; i2 = i1;
                    if (d < d0) { d1 = d0; i1 = i0; d0 = d; i0 = idx; }
                    else        { d1 = d;  i1 = idx; }
                } else { d2 = d; i2 = idx; }
            }
        }
        __syncthreads();
    }
    float s0 = sqrtf(fmaxf(d0, 0.f)), s1 = sqrtf(fmaxf(d1, 0.f)), s2 = sqrtf(fmaxf(d2, 0.f));
    float r0 = 1.f/(s0+1e-8f), r1 = 1.f/(s1+1e-8f), r2 = 1.f/(s2+1e-8f);
    float inv = 1.f/(r0+r1+r2);
    idx3[(size_t)t*3+0] = i0; idx3[(size_t)t*3+1] = i1; idx3[(size_t)t*3+2] = i2;
    w3[(size_t)t*3+0] = r0*inv; w3[(size_t)t*3+1] = r1*inv; w3[(size_t)t*3+2] = r2*inv;
}

// ---------------------------------------------------------------------------
// x[b,m,c] = relu(bn2(tu_lin2_w @ target_feature)) + three_interpolate(f_t)
extern "C" __global__ __launch_bounds__(C_) void k_feat(
    const float* __restrict__ tfeat, const float* __restrict__ w2,
    const float* __restrict__ g, const float* __restrict__ bb,
    const float* __restrict__ f_t, const int* __restrict__ idx3,
    const float* __restrict__ w3, float* __restrict__ x)
{
    int bm = blockIdx.x;
    int b  = bm / M_;
    int m  = bm - b * M_;
    int c  = threadIdx.x;
    const float* tf = tfeat + (size_t)b * C_ * M_ + m;
    const float* wr = w2 + (size_t)c * C_;
    float acc = 0.f;
#pragma unroll 8
    for (int j = 0; j < C_; ++j)
        acc = fmaf(wr[j], tf[(size_t)j * M_], acc);
    float y = fmaxf(fmaf(acc, g[c] * BNINV, bb[c]), 0.f);
    const float* fb = f_t + (size_t)b * N_ * C_;
    int   i0 = idx3[bm*3+0], i1 = idx3[bm*3+1], i2 = idx3[bm*3+2];
    float u0 = w3[bm*3+0],  u1 = w3[bm*3+1],  u2 = w3[bm*3+2];
    y += u0 * fb[(size_t)i0*C_ + c] + u1 * fb[(size_t)i1*C_ + c] + u2 * fb[(size_t)i2*C_ + c];
    x[(size_t)bm * C_ + c] = y;
}

// ---------------------------------------------------------------------------
// kNN among target points: 4 waves/block, each wave scans 1/4 of candidates
// for the same 64 queries (lane = query); 4-way stable merge at the end.
extern "C" __global__ __launch_bounds__(256) void k_knn(
    const float* __restrict__ txyz, int* __restrict__ out_knn)
{
    __shared__ float pd[4][64][K_+1];
    __shared__ int   pi[4][64][K_+1];
    __shared__ float sx[4][64], sy[4][64], sz[4][64];
    int tid = threadIdx.x;
    int w = tid >> 6;
    int l = tid & 63;
    int qbase = blockIdx.x * 64;
    int b = qbase / M_;
    const float* base = txyz + (size_t)b * M_ * 3;
    int m = (qbase - b*M_) + l;
    float qx = base[m*3+0], qy = base[m*3+1], qz = base[m*3+2];
    float bd[K_]; int bi[K_];
#pragma unroll
    for (int i = 0; i < K_; ++i) { bd[i] = 3e38f; bi[i] = 0; }
    const int RL = M_ / 4;
    int rbeg = w * RL;
    for (int cb = 0; cb < RL; cb += 64) {
        int j = rbeg + cb + l;
        sx[w][l] = base[j*3+0];
        sy[w][l] = base[j*3+1];
        sz[w][l] = base[j*3+2];
        __syncthreads();
#pragma unroll 4
        for (int jj = 0; jj < 64; ++jj) {
            float dx = sx[w][jj]-qx, dy = sy[w][jj]-qy, dz = sz[w][jj]-qz;
            float d = __fadd_rn(__fadd_rn(__fmul_rn(dx,dx), __fmul_rn(dy,dy)), __fmul_rn(dz,dz));
            if (d < bd[K_-1]) {                 // strict: keeps earlier index on ties
                bd[K_-1] = d; bi[K_-1] = rbeg + cb + jj;
#pragma unroll
                for (int p = K_-1; p > 0; --p) {
                    if (bd[p] < bd[p-1]) {
                        float td = bd[p]; bd[p] = bd[p-1]; bd[p-1] = td;
                        int   ti = bi[p]; bi[p] = bi[p-1]; bi[p-1] = ti;
                    }
                }
            }
        }
        __syncthreads();
    }
#pragma unroll
    for (int i = 0; i < K_; ++i) { pd[w][l][i] = bd[i]; pi[w][l][i] = bi[i]; }
    __syncthreads();
    if (tid < 64) {
        int p0 = 0, p1 = 0, p2 = 0, p3 = 0;
        size_t ob = (size_t)(qbase + tid) * K_;
        for (int i = 0; i < K_; ++i) {
            float d0 = pd[0][tid][p0], d1 = pd[1][tid][p1], d2 = pd[2][tid][p2], d3 = pd[3][tid][p3];
            int   j0 = pi[0][tid][p0], j1 = pi[1][tid][p1], j2 = pi[2][tid][p2], j3 = pi[3][tid][p3];
            bool t01 = (d1 < d0) || (d1 == d0 && j1 < j0);
            float da = t01 ? d1 : d0; int ja = t01 ? j1 : j0;
            bool t23 = (d3 < d2) || (d3 == d2 && j3 < j2);
            float db = t23 ? d3 : d2; int jb = t23 ? j3 : j2;
            bool tab = (db < da) || (db == da && jb < ja);
            out_knn[ob + i] = tab ? jb : ja;
            if (tab) { if (t23) ++p3; else ++p2; } else { if (t01) ++p1; else ++p0; }
        }
    }
}

// ---------------------------------------------------------------------------
// x1 = relu(bn(x @ W.T))
extern "C" __global__ __launch_bounds__(C_) void k_lin(
    const float* __restrict__ xin, const float* __restrict__ w,
    const float* __restrict__ g, const float* __restrict__ bb,
    float* __restrict__ xout)
{
    int bm = blockIdx.x;
    int c  = threadIdx.x;
    __shared__ float row[C_];
    row[c] = xin[(size_t)bm * C_ + c];
    __syncthreads();
    const float* wr = w + (size_t)c * C_;
    float acc = 0.f;
#pragma unroll 8
    for (int j = 0; j < C_; ++j) acc = fmaf(wr[j], row[j], acc);
    xout[(size_t)bm * C_ + c] = fmaxf(fmaf(acc, g[c]*BNINV, bb[c]), 0.f);
}

// ---------------------------------------------------------------------------
// q,k,v = x1 @ {wq,wk,wv}.T + bias
extern "C" __global__ __launch_bounds__(C_) void k_qkv(
    const float* __restrict__ x1,
    const float* __restrict__ wq, const float* __restrict__ bq,
    const float* __restrict__ wk, const float* __restrict__ bk,
    const float* __restrict__ wv, const float* __restrict__ bv,
    float* __restrict__ q, float* __restrict__ k, float* __restrict__ v)
{
    int bm = blockIdx.x;
    int c  = threadIdx.x;
    __shared__ float row[C_];
    row[c] = x1[(size_t)bm * C_ + c];
    __syncthreads();
    const float* wqr = wq + (size_t)c * C_;
    const float* wkr = wk + (size_t)c * C_;
    const float* wvr = wv + (size_t)c * C_;
    float aq = 0.f, ak = 0.f, av = 0.f;
#pragma unroll 4
    for (int j = 0; j < C_; ++j) {
        float r = row[j];
        aq = fmaf(wqr[j], r, aq);
        ak = fmaf(wkr[j], r, ak);
        av = fmaf(wvr[j], r, av);
    }
    q[(size_t)bm*C_+c] = aq + bq[c];
    k[(size_t)bm*C_+c] = ak + bk[c];
    v[(size_t)bm*C_+c] = av + bv[c];
}

// ---------------------------------------------------------------------------
// Fused vector attention + bn2 + lin3 + bn3 + residual + output transpose
extern "C" __global__ __launch_bounds__(C_) void k_attn(
    const float* __restrict__ q, const float* __restrict__ kf, const float* __restrict__ vf,
    const int* __restrict__ knn, const float* __restrict__ txyz,
    const float* __restrict__ p1w, const float* __restrict__ p1b,
    const float* __restrict__ pbg, const float* __restrict__ pbb,
    const float* __restrict__ p2w, const float* __restrict__ p2b,
    const float* __restrict__ wb1g, const float* __restrict__ wb1b,
    const float* __restrict__ wl1, const float* __restrict__ wl1b,
    const float* __restrict__ wb2g, const float* __restrict__ wb2b,
    const float* __restrict__ wl2, const float* __restrict__ wl2b,
    const float* __restrict__ bn2g, const float* __restrict__ bn2b,
    const float* __restrict__ l3w, const float* __restrict__ bn3g, const float* __restrict__ bn3b,
    const float* __restrict__ xid, float* __restrict__ out)
{
    int bm = blockIdx.x;
    int b  = bm / M_;
    int m  = bm - b * M_;
    int c  = threadIdx.x;

    __shared__ float sv[K_][C_];
    __shared__ float tsh[C_];
    __shared__ float ash[CS_];
    __shared__ float wsh[K_][CS_];
    __shared__ float x2sh[C_];

    float qc = q[(size_t)bm*C_ + c];
    float qx = txyz[(size_t)bm*3+0], qy = txyz[(size_t)bm*3+1], qz = txyz[(size_t)bm*3+2];
    float p2w0 = p2w[c*3+0], p2w1 = p2w[c*3+1], p2w2 = p2w[c*3+2], p2bc = p2b[c];
    float b1s = wb1g[c]*BNINV, b1b = wb1b[c];
    float a00=p1w[0],a01=p1w[1],a02=p1w[2],a10=p1w[3],a11=p1w[4],a12=p1w[5],a20=p1w[6],a21=p1w[7],a22=p1w[8];
    float pb0=p1b[0], pb1=p1b[1], pb2=p1b[2];
    float g0=pbg[0]*BNINV, g1=pbg[1]*BNINV, g2=pbg[2]*BNINV;
    float hb0=pbb[0], hb1=pbb[1], hb2=pbb[2];

    const float* txb = txyz + (size_t)b*M_*3;

    for (int t = 0; t < K_; ++t) {
        int nb = knn[(size_t)bm*K_ + t];
        float dx = txb[nb*3+0]-qx, dy = txb[nb*3+1]-qy, dz = txb[nb*3+2]-qz;
        float h0 = fmaxf(fmaf(fmaf(a02,dz, fmaf(a01,dy, fmaf(a00,dx, pb0))), g0, hb0), 0.f);
        float h1 = fmaxf(fmaf(fmaf(a12,dz, fmaf(a11,dy, fmaf(a10,dx, pb1))), g1, hb1), 0.f);
        float h2 = fmaxf(fmaf(fmaf(a22,dz, fmaf(a21,dy, fmaf(a20,dx, pb2))), g2, hb2), 0.f);
        float pr = fmaf(p2w2,h2, fmaf(p2w1,h1, fmaf(p2w0,h0, p2bc)));
        size_t nrow = ((size_t)b*M_ + nb)*C_ + c;
        float r = kf[nrow] - qc + pr;
        tsh[c]   = fmaxf(fmaf(r, b1s, b1b), 0.f);
        sv[t][c] = vf[nrow] + pr;
        __syncthreads();
        // 16x128 matvec, all 128 threads: s = tid>>3 (0..15), u = tid&7
        {
            int s = c >> 3, u = c & 7;
            float a = 0.f;
#pragma unroll
            for (int i = 0; i < 16; ++i)
                a = fmaf(wl1[(size_t)s*C_ + u + 8*i], tsh[u + 8*i], a);
            a += __shfl_down(a, 4, 8);
            a += __shfl_down(a, 2, 8);
            a += __shfl_down(a, 1, 8);
            if (u == 0)
                ash[s] = fmaxf(fmaf(a + wl1b[s], wb2g[s]*BNINV, wb2b[s]), 0.f);
        }
        __syncthreads();
        if (c < CS_) {
            float a = wl2b[c];
#pragma unroll
            for (int j = 0; j < CS_; ++j)
                a = fmaf(wl2[c*CS_ + j], ash[j], a);
            wsh[t][c] = a;
        }
        __syncthreads();
    }
    // softmax over K per s
    if (c < CS_) {
        float mx = -3e38f;
#pragma unroll
        for (int t = 0; t < K_; ++t) mx = fmaxf(mx, wsh[t][c]);
        float ssum = 0.f;
#pragma unroll
        for (int t = 0; t < K_; ++t) { float e = __expf(wsh[t][c] - mx); wsh[t][c] = e; ssum += e; }
        float inv = 1.f / ssum;
#pragma unroll
        for (int t = 0; t < K_; ++t) wsh[t][c] *= inv;
    }
    __syncthreads();
    float agg = 0.f;
    int s_idx = c & (CS_-1);
#pragma unroll
    for (int t = 0; t < K_; ++t) agg = fmaf(sv[t][c], wsh[t][s_idx], agg);
    float x2 = fmaxf(fmaf(agg, bn2g[c]*BNINV, bn2b[c]), 0.f);
    x2sh[c] = x2;
    __syncthreads();
    const float* l3r = l3w + (size_t)c*C_;
    float a3 = 0.f;
#pragma unroll 8
    for (int j = 0; j < C_; ++j) a3 = fmaf(l3r[j], x2sh[j], a3);
    float x3 = fmaf(a3, bn3g[c]*BNINV, bn3b[c]);
    float o  = fmaxf(x3 + xid[(size_t)bm*C_ + c], 0.f);
    out[(size_t)b*C_*M_ + (size_t)c*M_ + m] = o;
}

// ---------------------------------------------------------------------------
extern "C" void kernel_launch(void* const* d_in, const int* in_sizes, int n_in,
                              void* d_out, int out_size, void* d_ws, size_t ws_size,
                              hipStream_t stream)
{
    const float* xyz   = (const float*)d_in[0];
    const float* feat  = (const float*)d_in[1];
    const float* txyz  = (const float*)d_in[2];
    const float* tfeat = (const float*)d_in[3];
    const float* tu1w  = (const float*)d_in[4];
    const float* tu1g  = (const float*)d_in[5];
    const float* tu1b  = (const float*)d_in[6];
    const float* tu2w  = (const float*)d_in[7];
    const float* tu2g  = (const float*)d_in[8];
    const float* tu2b  = (const float*)d_in[9];
    const float* bl1w  = (const float*)d_in[10];
    const float* bl1g  = (const float*)d_in[11];
    const float* bl1b  = (const float*)d_in[12];
    const float* wq    = (const float*)d_in[13];
    const float* bq    = (const float*)d_in[14];
    const float* wk    = (const float*)d_in[15];
    const float* bk    = (const float*)d_in[16];
    const float* wv    = (const float*)d_in[17];
    const float* bv    = (const float*)d_in[18];
    const float* p1w   = (const float*)d_in[19];
    const float* p1b   = (const float*)d_in[20];
    const float* pbg   = (const float*)d_in[21];
    const float* pbb   = (const float*)d_in[22];
    const float* p2w   = (const float*)d_in[23];
    const float* p2b   = (const float*)d_in[24];
    const float* wb1g  = (const float*)d_in[25];
    const float* wb1b  = (const float*)d_in[26];
    const float* wl1   = (const float*)d_in[27];
    const float* wl1b  = (const float*)d_in[28];
    const float* wb2g  = (const float*)d_in[29];
    const float* wb2b  = (const float*)d_in[30];
    const float* wl2   = (const float*)d_in[31];
    const float* wl2b  = (const float*)d_in[32];
    const float* bn2g  = (const float*)d_in[33];
    const float* bn2b  = (const float*)d_in[34];
    const float* l3w   = (const float*)d_in[35];
    const float* bn3g  = (const float*)d_in[36];
    const float* bn3b  = (const float*)d_in[37];

    char* ws = (char*)d_ws;
    size_t off = 0;
    auto alloc = [&](size_t bytes) { void* p = ws + off; off += (bytes + 255) & ~(size_t)255; return p; };
    float* f_t  = (float*)alloc(sizeof(float) * B_ * N_ * C_);
    int*   idx3 = (int*)  alloc(sizeof(int)   * B_ * M_ * 3);
    float* w3   = (float*)alloc(sizeof(float) * B_ * M_ * 3);
    float* x    = (float*)alloc(sizeof(float) * B_ * M_ * C_);
    float* x1   = (float*)alloc(sizeof(float) * B_ * M_ * C_);
    float* qb   = (float*)alloc(sizeof(float) * B_ * M_ * C_);
    float* kb   = (float*)alloc(sizeof(float) * B_ * M_ * C_);
    float* vb   = (float*)alloc(sizeof(float) * B_ * M_ * C_);
    int*   knn  = (int*)  alloc(sizeof(int)   * B_ * M_ * K_);

    k_f       <<<B_*N_,     C_,  0, stream>>>(feat, tu1w, tu1g, tu1b, f_t);
    k_three_nn<<<B_*M_/64,  64,  0, stream>>>(xyz, txyz, idx3, w3);
    k_feat    <<<B_*M_,     C_,  0, stream>>>(tfeat, tu2w, tu2g, tu2b, f_t, idx3, w3, x);
    k_knn     <<<B_*M_/64,  256, 0, stream>>>(txyz, knn);
    k_lin     <<<B_*M_,     C_,  0, stream>>>(x, bl1w, bl1g, bl1b, x1);
    k_qkv     <<<B_*M_,     C_,  0, stream>>>(x1, wq, bq, wk, bk, wv, bv, qb, kb, vb);
    k_attn    <<<B_*M_,     C_,  0, stream>>>(qb, kb, vb, knn, txyz,
                                              p1w, p1b, pbg, pbb, p2w, p2b,
                                              wb1g, wb1b, wl1, wl1b, wb2g, wb2b, wl2, wl2b,
                                              bn2g, bn2b, l3w, bn3g, bn3b,
                                              x, (float*)d_out);
}

// Round 5
// 1622.166 us; speedup vs baseline: 1.4142x; 1.4142x over previous
//
#include <hip/hip_runtime.h>
#include <cstddef>
#include <cstdint>

#define B_  2
#define N_  2048
#define M_  8192
#define C1_ 256
#define C_  128
#define K_  16
#define CS_ 16

// 1/sqrt(1+1e-5)
#define BNINV 0.9999950000374997f

// ---------------------------------------------------------------------------
// f_t[b,n,c] = relu(bn1(tu_lin1_w @ feature))   (stored point-major for coalesced gather)
extern "C" __global__ __launch_bounds__(C_) void k_f(
    const float* __restrict__ feature, const float* __restrict__ w,
    const float* __restrict__ g, const float* __restrict__ bb,
    float* __restrict__ f_t)
{
    int bn = blockIdx.x;            // b*N_ + n
    int b  = bn / N_;
    int n  = bn - b * N_;
    int c  = threadIdx.x;
    const float* fp = feature + (size_t)b * C1_ * N_ + n;
    const float* wr = w + (size_t)c * C1_;
    float acc = 0.f;
#pragma unroll 8
    for (int j = 0; j < C1_; ++j)
        acc = fmaf(wr[j], fp[(size_t)j * N_], acc);
    f_t[(size_t)bn * C_ + c] = fmaxf(fmaf(acc, g[c] * BNINV, bb[c]), 0.f);
}

// ---------------------------------------------------------------------------
// three_nn: one wave per target point. 64 lanes scan N_=2048 candidates
// (lane-strided, coalesced); per-lane top-3 as packed u64 (d_bits<<32 | idx);
// 3 rounds of wave-min extraction. Exact (d, idx) lexicographic order.
extern "C" __global__ __launch_bounds__(256) void k_three_nn(
    const float* __restrict__ xyz, const float* __restrict__ txyz,
    int* __restrict__ idx3, float* __restrict__ w3)
{
    int q    = blockIdx.x * 4 + (threadIdx.x >> 6);   // 0..B*M-1
    int lane = threadIdx.x & 63;
    int b    = q / M_;
    const float* src = xyz + (size_t)b * N_ * 3;
    float qx = txyz[(size_t)q*3+0], qy = txyz[(size_t)q*3+1], qz = txyz[(size_t)q*3+2];

    unsigned long long p0 = ~0ULL, p1 = ~0ULL, p2 = ~0ULL;
    for (int i = 0; i < N_/64; ++i) {
        int j = lane + (i << 6);
        float dx = src[j*3+0]-qx, dy = src[j*3+1]-qy, dz = src[j*3+2]-qz;
        float d = __fadd_rn(__fadd_rn(__fmul_rn(dx,dx), __fmul_rn(dy,dy)), __fmul_rn(dz,dz));
        unsigned long long key = ((unsigned long long)__float_as_uint(d) << 32) | (unsigned)j;
        if (key < p2) {
            p2 = key;
            if (p2 < p1) { unsigned long long t = p1; p1 = p2; p2 = t; }
            if (p1 < p0) { unsigned long long t = p0; p0 = p1; p1 = t; }
        }
    }
    unsigned long long wmin[3];
    unsigned long long h = p0;
#pragma unroll
    for (int r = 0; r < 3; ++r) {
        unsigned long long w = h;
#pragma unroll
        for (int s = 1; s < 64; s <<= 1) {
            unsigned long long o = __shfl_xor(w, s, 64);
            w = (o < w) ? o : w;
        }
        wmin[r] = w;            // uniform across lanes
        if (h == w) { p0 = p1; p1 = p2; p2 = ~0ULL; h = p0; }
    }
    if (lane == 0) {
        float d0 = __uint_as_float((unsigned)(wmin[0] >> 32));
        float d1 = __uint_as_float((unsigned)(wmin[1] >> 32));
        float d2 = __uint_as_float((unsigned)(wmin[2] >> 32));
        float s0 = sqrtf(fmaxf(d0, 0.f)), s1 = sqrtf(fmaxf(d1, 0.f)), s2 = sqrtf(fmaxf(d2, 0.f));
        float r0 = 1.f/(s0+1e-8f), r1 = 1.f/(s1+1e-8f), r2 = 1.f/(s2+1e-8f);
        float inv = 1.f/(r0+r1+r2);
        idx3[(size_t)q*3+0] = (int)(unsigned)wmin[0];
        idx3[(size_t)q*3+1] = (int)(unsigned)wmin[1];
        idx3[(size_t)q*3+2] = (int)(unsigned)wmin[2];
        w3[(size_t)q*3+0] = r0*inv; w3[(size_t)q*3+1] = r1*inv; w3[(size_t)q*3+2] = r2*inv;
    }
}

// ---------------------------------------------------------------------------
// x[b,m,c] = relu(bn2(tu_lin2_w @ target_feature)) + three_interpolate(f_t)
extern "C" __global__ __launch_bounds__(C_) void k_feat(
    const float* __restrict__ tfeat, const float* __restrict__ w2,
    const float* __restrict__ g, const float* __restrict__ bb,
    const float* __restrict__ f_t, const int* __restrict__ idx3,
    const float* __restrict__ w3, float* __restrict__ x)
{
    int bm = blockIdx.x;
    int b  = bm / M_;
    int m  = bm - b * M_;
    int c  = threadIdx.x;
    const float* tf = tfeat + (size_t)b * C_ * M_ + m;
    const float* wr = w2 + (size_t)c * C_;
    float acc = 0.f;
#pragma unroll 8
    for (int j = 0; j < C_; ++j)
        acc = fmaf(wr[j], tf[(size_t)j * M_], acc);
    float y = fmaxf(fmaf(acc, g[c] * BNINV, bb[c]), 0.f);
    const float* fb = f_t + (size_t)b * N_ * C_;
    int   i0 = idx3[bm*3+0], i1 = idx3[bm*3+1], i2 = idx3[bm*3+2];
    float u0 = w3[bm*3+0],  u1 = w3[bm*3+1],  u2 = w3[bm*3+2];
    y += u0 * fb[(size_t)i0*C_ + c] + u1 * fb[(size_t)i1*C_ + c] + u2 * fb[(size_t)i2*C_ + c];
    x[(size_t)bm * C_ + c] = y;
}

// ---------------------------------------------------------------------------
// kNN among target points: one wave per query. 64 lanes scan M_=8192 candidates
// (lane-strided, coalesced); per-lane sorted top-16 of packed u64 keys
// (d_bits<<32 | idx -> exact (d,idx) lexicographic = lax.top_k tie-break);
// 16 rounds of wave-wide min-extraction merge 64 lists into the global top-16.
extern "C" __global__ __launch_bounds__(256) void k_knn(
    const float* __restrict__ txyz, int* __restrict__ out_knn)
{
    int q    = blockIdx.x * 4 + (threadIdx.x >> 6);   // 0..B*M-1
    int lane = threadIdx.x & 63;
    int b    = q / M_;
    int m    = q - b * M_;
    const float* base = txyz + (size_t)b * M_ * 3;
    float qx = base[m*3+0], qy = base[m*3+1], qz = base[m*3+2];

    unsigned long long p[K_];
#pragma unroll
    for (int i = 0; i < K_; ++i) p[i] = ~0ULL;

    for (int i = 0; i < M_/64; ++i) {
        int j = lane + (i << 6);
        float dx = base[j*3+0]-qx, dy = base[j*3+1]-qy, dz = base[j*3+2]-qz;
        float d = __fadd_rn(__fadd_rn(__fmul_rn(dx,dx), __fmul_rn(dy,dy)), __fmul_rn(dz,dz));
        unsigned long long key = ((unsigned long long)__float_as_uint(d) << 32) | (unsigned)j;
        if (key < p[K_-1]) {
            p[K_-1] = key;
#pragma unroll
            for (int t = K_-1; t > 0; --t) {
                unsigned long long a = p[t-1], c2 = p[t];
                bool sw = c2 < a;
                p[t-1] = sw ? c2 : a;
                p[t]   = sw ? a  : c2;
            }
        }
    }

    // merge 64 sorted lists: 16 rounds of wave-min + pop
    unsigned long long keep = 0;
    unsigned long long h = p[0];
#pragma unroll
    for (int r = 0; r < K_; ++r) {
        unsigned long long w = h;
#pragma unroll
        for (int s = 1; s < 64; s <<= 1) {
            unsigned long long o = __shfl_xor(w, s, 64);
            w = (o < w) ? o : w;
        }
        if (lane == r) keep = w;
        if (h == w) {               // unique key -> exactly one lane pops
#pragma unroll
            for (int t = 0; t < K_-1; ++t) p[t] = p[t+1];
            p[K_-1] = ~0ULL;
            h = p[0];
        }
    }
    if (lane < K_)
        out_knn[(size_t)q*K_ + lane] = (int)(unsigned)keep;
}

// ---------------------------------------------------------------------------
// x1 = relu(bn(x @ W.T))
extern "C" __global__ __launch_bounds__(C_) void k_lin(
    const float* __restrict__ xin, const float* __restrict__ w,
    const float* __restrict__ g, const float* __restrict__ bb,
    float* __restrict__ xout)
{
    int bm = blockIdx.x;
    int c  = threadIdx.x;
    __shared__ float row[C_];
    row[c] = xin[(size_t)bm * C_ + c];
    __syncthreads();
    const float* wr = w + (size_t)c * C_;
    float acc = 0.f;
#pragma unroll 8
    for (int j = 0; j < C_; ++j) acc = fmaf(wr[j], row[j], acc);
    xout[(size_t)bm * C_ + c] = fmaxf(fmaf(acc, g[c]*BNINV, bb[c]), 0.f);
}

// ---------------------------------------------------------------------------
// q,k,v = x1 @ {wq,wk,wv}.T + bias
extern "C" __global__ __launch_bounds__(C_) void k_qkv(
    const float* __restrict__ x1,
    const float* __restrict__ wq, const float* __restrict__ bq,
    const float* __restrict__ wk, const float* __restrict__ bk,
    const float* __restrict__ wv, const float* __restrict__ bv,
    float* __restrict__ q, float* __restrict__ k, float* __restrict__ v)
{
    int bm = blockIdx.x;
    int c  = threadIdx.x;
    __shared__ float row[C_];
    row[c] = x1[(size_t)bm * C_ + c];
    __syncthreads();
    const float* wqr = wq + (size_t)c * C_;
    const float* wkr = wk + (size_t)c * C_;
    const float* wvr = wv + (size_t)c * C_;
    float aq = 0.f, ak = 0.f, av = 0.f;
#pragma unroll 4
    for (int j = 0; j < C_; ++j) {
        float r = row[j];
        aq = fmaf(wqr[j], r, aq);
        ak = fmaf(wkr[j], r, ak);
        av = fmaf(wvr[j], r, av);
    }
    q[(size_t)bm*C_+c] = aq + bq[c];
    k[(size_t)bm*C_+c] = ak + bk[c];
    v[(size_t)bm*C_+c] = av + bv[c];
}

// ---------------------------------------------------------------------------
// Fused vector attention + bn2 + lin3 + bn3 + residual + output transpose
extern "C" __global__ __launch_bounds__(C_) void k_attn(
    const float* __restrict__ q, const float* __restrict__ kf, const float* __restrict__ vf,
    const int* __restrict__ knn, const float* __restrict__ txyz,
    const float* __restrict__ p1w, const float* __restrict__ p1b,
    const float* __restrict__ pbg, const float* __restrict__ pbb,
    const float* __restrict__ p2w, const float* __restrict__ p2b,
    const float* __restrict__ wb1g, const float* __restrict__ wb1b,
    const float* __restrict__ wl1, const float* __restrict__ wl1b,
    const float* __restrict__ wb2g, const float* __restrict__ wb2b,
    const float* __restrict__ wl2, const float* __restrict__ wl2b,
    const float* __restrict__ bn2g, const float* __restrict__ bn2b,
    const float* __restrict__ l3w, const float* __restrict__ bn3g, const float* __restrict__ bn3b,
    const float* __restrict__ xid, float* __restrict__ out)
{
    int bm = blockIdx.x;
    int b  = bm / M_;
    int m  = bm - b * M_;
    int c  = threadIdx.x;

    __shared__ float sv[K_][C_];
    __shared__ float tsh[C_];
    __shared__ float ash[CS_];
    __shared__ float wsh[K_][CS_];
    __shared__ float x2sh[C_];

    float qc = q[(size_t)bm*C_ + c];
    float qx = txyz[(size_t)bm*3+0], qy = txyz[(size_t)bm*3+1], qz = txyz[(size_t)bm*3+2];
    float p2w0 = p2w[c*3+0], p2w1 = p2w[c*3+1], p2w2 = p2w[c*3+2], p2bc = p2b[c];
    float b1s = wb1g[c]*BNINV, b1b = wb1b[c];
    float a00=p1w[0],a01=p1w[1],a02=p1w[2],a10=p1w[3],a11=p1w[4],a12=p1w[5],a20=p1w[6],a21=p1w[7],a22=p1w[8];
    float pb0=p1b[0], pb1=p1b[1], pb2=p1b[2];
    float g0=pbg[0]*BNINV, g1=pbg[1]*BNINV, g2=pbg[2]*BNINV;
    float hb0=pbb[0], hb1=pbb[1], hb2=pbb[2];

    const float* txb = txyz + (size_t)b*M_*3;

    for (int t = 0; t < K_; ++t) {
        int nb = knn[(size_t)bm*K_ + t];
        float dx = txb[nb*3+0]-qx, dy = txb[nb*3+1]-qy, dz = txb[nb*3+2]-qz;
        float h0 = fmaxf(fmaf(fmaf(a02,dz, fmaf(a01,dy, fmaf(a00,dx, pb0))), g0, hb0), 0.f);
        float h1 = fmaxf(fmaf(fmaf(a12,dz, fmaf(a11,dy, fmaf(a10,dx, pb1))), g1, hb1), 0.f);
        float h2 = fmaxf(fmaf(fmaf(a22,dz, fmaf(a21,dy, fmaf(a20,dx, pb2))), g2, hb2), 0.f);
        float pr = fmaf(p2w2,h2, fmaf(p2w1,h1, fmaf(p2w0,h0, p2bc)));
        size_t nrow = ((size_t)b*M_ + nb)*C_ + c;
        float r = kf[nrow] - qc + pr;
        tsh[c]   = fmaxf(fmaf(r, b1s, b1b), 0.f);
        sv[t][c] = vf[nrow] + pr;
        __syncthreads();
        // 16x128 matvec, all 128 threads: s = tid>>3 (0..15), u = tid&7
        {
            int s = c >> 3, u = c & 7;
            float a = 0.f;
#pragma unroll
            for (int i = 0; i < 16; ++i)
                a = fmaf(wl1[(size_t)s*C_ + u + 8*i], tsh[u + 8*i], a);
            a += __shfl_down(a, 4, 8);
            a += __shfl_down(a, 2, 8);
            a += __shfl_down(a, 1, 8);
            if (u == 0)
                ash[s] = fmaxf(fmaf(a + wl1b[s], wb2g[s]*BNINV, wb2b[s]), 0.f);
        }
        __syncthreads();
        if (c < CS_) {
            float a = wl2b[c];
#pragma unroll
            for (int j = 0; j < CS_; ++j)
                a = fmaf(wl2[c*CS_ + j], ash[j], a);
            wsh[t][c] = a;
        }
        __syncthreads();
    }
    // softmax over K per s
    if (c < CS_) {
        float mx = -3e38f;
#pragma unroll
        for (int t = 0; t < K_; ++t) mx = fmaxf(mx, wsh[t][c]);
        float ssum = 0.f;
#pragma unroll
        for (int t = 0; t < K_; ++t) { float e = __expf(wsh[t][c] - mx); wsh[t][c] = e; ssum += e; }
        float inv = 1.f / ssum;
#pragma unroll
        for (int t = 0; t < K_; ++t) wsh[t][c] *= inv;
    }
    __syncthreads();
    float agg = 0.f;
    int s_idx = c & (CS_-1);
#pragma unroll
    for (int t = 0; t < K_; ++t) agg = fmaf(sv[t][c], wsh[t][s_idx], agg);
    float x2 = fmaxf(fmaf(agg, bn2g[c]*BNINV, bn2b[c]), 0.f);
    x2sh[c] = x2;
    __syncthreads();
    const float* l3r = l3w + (size_t)c*C_;
    float a3 = 0.f;
#pragma unroll 8
    for (int j = 0; j < C_; ++j) a3 = fmaf(l3r[j], x2sh[j], a3);
    float x3 = fmaf(a3, bn3g[c]*BNINV, bn3b[c]);
    float o  = fmaxf(x3 + xid[(size_t)bm*C_ + c], 0.f);
    out[(size_t)b*C_*M_ + (size_t)c*M_ + m] = o;
}

// ---------------------------------------------------------------------------
extern "C" void kernel_launch(void* const* d_in, const int* in_sizes, int n_in,
                              void* d_out, int out_size, void* d_ws, size_t ws_size,
                              hipStream_t stream)
{
    const float* xyz   = (const float*)d_in[0];
    const float* feat  = (const float*)d_in[1];
    const float* txyz  = (const float*)d_in[2];
    const float* tfeat = (const float*)d_in[3];
    const float* tu1w  = (const float*)d_in[4];
    const float* tu1g  = (const float*)d_in[5];
    const float* tu1b  = (const float*)d_in[6];
    const float* tu2w  = (const float*)d_in[7];
    const float* tu2g  = (const float*)d_in[8];
    const float* tu2b  = (const float*)d_in[9];
    const float* bl1w  = (const float*)d_in[10];
    const float* bl1g  = (const float*)d_in[11];
    const float* bl1b  = (const float*)d_in[12];
    const float* wq    = (const float*)d_in[13];
    const float* bq    = (const float*)d_in[14];
    const float* wk    = (const float*)d_in[15];
    const float* bk    = (const float*)d_in[16];
    const float* wv    = (const float*)d_in[17];
    const float* bv    = (const float*)d_in[18];
    const float* p1w   = (const float*)d_in[19];
    const float* p1b   = (const float*)d_in[20];
    const float* pbg   = (const float*)d_in[21];
    const float* pbb   = (const float*)d_in[22];
    const float* p2w   = (const float*)d_in[23];
    const float* p2b   = (const float*)d_in[24];
    const float* wb1g  = (const float*)d_in[25];
    const float* wb1b  = (const float*)d_in[26];
    const float* wl1   = (const float*)d_in[27];
    const float* wl1b  = (const float*)d_in[28];
    const float* wb2g  = (const float*)d_in[29];
    const float* wb2b  = (const float*)d_in[30];
    const float* wl2   = (const float*)d_in[31];
    const float* wl2b  = (const float*)d_in[32];
    const float* bn2g  = (const float*)d_in[33];
    const float* bn2b  = (const float*)d_in[34];
    const float* l3w   = (const float*)d_in[35];
    const float* bn3g  = (const float*)d_in[36];
    const float* bn3b  = (const float*)d_in[37];

    char* ws = (char*)d_ws;
    size_t off = 0;
    auto alloc = [&](size_t bytes) { void* p = ws + off; off += (bytes + 255) & ~(size_t)255; return p; };
    float* f_t  = (float*)alloc(sizeof(float) * B_ * N_ * C_);
    int*   idx3 = (int*)  alloc(sizeof(int)   * B_ * M_ * 3);
    float* w3   = (float*)alloc(sizeof(float) * B_ * M_ * 3);
    float* x    = (float*)alloc(sizeof(float) * B_ * M_ * C_);
    float* x1   = (float*)alloc(sizeof(float) * B_ * M_ * C_);
    float* qb   = (float*)alloc(sizeof(float) * B_ * M_ * C_);
    float* kb   = (float*)alloc(sizeof(float) * B_ * M_ * C_);
    float* vb   = (float*)alloc(sizeof(float) * B_ * M_ * C_);
    int*   knn  = (int*)  alloc(sizeof(int)   * B_ * M_ * K_);

    k_f       <<<B_*N_,      C_,  0, stream>>>(feat, tu1w, tu1g, tu1b, f_t);
    k_three_nn<<<B_*M_/4,    256, 0, stream>>>(xyz, txyz, idx3, w3);
    k_feat    <<<B_*M_,      C_,  0, stream>>>(tfeat, tu2w, tu2g, tu2b, f_t, idx3, w3, x);
    k_knn     <<<B_*M_/4,    256, 0, stream>>>(txyz, knn);
    k_lin     <<<B_*M_,      C_,  0, stream>>>(x, bl1w, bl1g, bl1b, x1);
    k_qkv     <<<B_*M_,      C_,  0, stream>>>(x1, wq, bq, wk, bk, wv, bv, qb, kb, vb);
    k_attn    <<<B_*M_,      C_,  0, stream>>>(qb, kb, vb, knn, txyz,
                                               p1w, p1b, pbg, pbb, p2w, p2b,
                                               wb1g, wb1b, wl1, wl1b, wb2g, wb2b, wl2, wl2b,
                                               bn2g, bn2b, l3w, bn3g, bn3b,
                                               x, (float*)d_out);
}

// Round 6
// 679.062 us; speedup vs baseline: 3.3784x; 2.3888x over previous
//
#include <hip/hip_runtime.h>
#include <cstddef>
#include <cstdint>

#define B_  2
#define N_  2048
#define M_  8192
#define C1_ 256
#define C_  128
#define K_  16
#define CS_ 16

// 1/sqrt(1+1e-5)
#define BNINV 0.9999950000374997f

// ======================= tiled fp32 GEMM machinery =========================
// BM=BN=128, BK=32, 256 threads, 8x8 micro-tile per thread.
// LDS tiles stored [BK][BM(+pad)] as float4 with row stride 33 float4 (132 f).
#define LDSS 33   // float4 stride per k-row

__device__ __forceinline__ void stage_direct(float4* Ls4, const float4* src4,
                                             size_t row_stride4, int k0,
                                             size_t col0_4, int t)
{
#pragma unroll
    for (int i = 0; i < 4; ++i) {
        int idx = t + i * 256;          // 0..1023
        int kk = idx >> 5, f4 = idx & 31;
        Ls4[kk * LDSS + f4] = src4[(size_t)(k0 + kk) * row_stride4 + col0_4 + f4];
    }
}

// src row-major [rows][ldk]; stage 128 rows starting at row0, k-range [k0,k0+32)
__device__ __forceinline__ void stage_transpose(float* Lsf, const float* src,
                                                int row0, int ldk, int k0, int t)
{
    int u = t & 7, r = t >> 3;          // u: k-quad, r: 0..31
#pragma unroll
    for (int i = 0; i < 4; ++i) {
        int row = r + i * 32;
        float4 v = *(const float4*)(src + (size_t)(row0 + row) * ldk + k0 + u * 4);
        Lsf[(u * 4 + 0) * 132 + row] = v.x;
        Lsf[(u * 4 + 1) * 132 + row] = v.y;
        Lsf[(u * 4 + 2) * 132 + row] = v.z;
        Lsf[(u * 4 + 3) * 132 + row] = v.w;
    }
}

__device__ __forceinline__ void gemm_step(const float4* As4, const float4* Bs4,
                                          int tm, int tn, float acc[8][8])
{
#pragma unroll 4
    for (int kk = 0; kk < 32; ++kk) {
        float4 a0 = As4[kk * LDSS + tm * 2];
        float4 a1 = As4[kk * LDSS + tm * 2 + 1];
        float4 b0 = Bs4[kk * LDSS + tn * 2];
        float4 b1 = Bs4[kk * LDSS + tn * 2 + 1];
        float av[8] = {a0.x,a0.y,a0.z,a0.w,a1.x,a1.y,a1.z,a1.w};
        float bv[8] = {b0.x,b0.y,b0.z,b0.w,b1.x,b1.y,b1.z,b1.w};
#pragma unroll
        for (int i = 0; i < 8; ++i)
#pragma unroll
            for (int j = 0; j < 8; ++j)
                acc[i][j] = fmaf(av[i], bv[j], acc[i][j]);
    }
}

__device__ __forceinline__ void load8(const float* p, float* v)
{
    float4 a = *(const float4*)p, b = *(const float4*)(p + 4);
    v[0]=a.x; v[1]=a.y; v[2]=a.z; v[3]=a.w; v[4]=b.x; v[5]=b.y; v[6]=b.z; v[7]=b.w;
}
__device__ __forceinline__ void store8(float* p, const float* v)
{
    *(float4*)p       = make_float4(v[0],v[1],v[2],v[3]);
    *(float4*)(p + 4) = make_float4(v[4],v[5],v[6],v[7]);
}

// ---------------------------------------------------------------------------
// f_t[bn][c] = relu(bn1(sum_j W1[c][j] * F[b][j][n]))   (A direct, K=256)
extern "C" __global__ __launch_bounds__(256) void k_f(
    const float* __restrict__ feature, const float* __restrict__ w,
    const float* __restrict__ g, const float* __restrict__ bb,
    float* __restrict__ f_t)
{
    __shared__ float4 As4[32 * LDSS], Bs4[32 * LDSS];
    int t = threadIdx.x, tm = t >> 4, tn = t & 15;
    int m0 = blockIdx.x * 128;
    int b = m0 >> 11;
    size_t col0_4 = (size_t)(m0 & (N_ - 1)) >> 2;
    const float4* src4 = (const float4*)feature + (size_t)b * C1_ * (N_ / 4);
    float acc[8][8] = {};
    for (int k0 = 0; k0 < C1_; k0 += 32) {
        stage_direct(As4, src4, N_ / 4, k0, col0_4, t);
        stage_transpose((float*)Bs4, w, 0, C1_, k0, t);
        __syncthreads();
        gemm_step(As4, Bs4, tm, tn, acc);
        __syncthreads();
    }
    int c0 = tn * 8;
    float gc[8], bc[8];
    load8(g + c0, gc); load8(bb + c0, bc);
#pragma unroll
    for (int mm = 0; mm < 8; ++mm) {
        int m = m0 + tm * 8 + mm;
        float o[8];
#pragma unroll
        for (int j = 0; j < 8; ++j)
            o[j] = fmaxf(fmaf(acc[mm][j], gc[j] * BNINV, bc[j]), 0.f);
        store8(f_t + (size_t)m * C_ + c0, o);
    }
}

// ---------------------------------------------------------------------------
// three_nn (wave/query, packed u64 keys) — unchanged from round 1
extern "C" __global__ __launch_bounds__(256) void k_three_nn(
    const float* __restrict__ xyz, const float* __restrict__ txyz,
    int* __restrict__ idx3, float* __restrict__ w3)
{
    int q    = blockIdx.x * 4 + (threadIdx.x >> 6);
    int lane = threadIdx.x & 63;
    int b    = q / M_;
    const float* src = xyz + (size_t)b * N_ * 3;
    float qx = txyz[(size_t)q*3+0], qy = txyz[(size_t)q*3+1], qz = txyz[(size_t)q*3+2];

    unsigned long long p0 = ~0ULL, p1 = ~0ULL, p2 = ~0ULL;
    for (int i = 0; i < N_/64; ++i) {
        int j = lane + (i << 6);
        float dx = src[j*3+0]-qx, dy = src[j*3+1]-qy, dz = src[j*3+2]-qz;
        float d = __fadd_rn(__fadd_rn(__fmul_rn(dx,dx), __fmul_rn(dy,dy)), __fmul_rn(dz,dz));
        unsigned long long key = ((unsigned long long)__float_as_uint(d) << 32) | (unsigned)j;
        if (key < p2) {
            p2 = key;
            if (p2 < p1) { unsigned long long t = p1; p1 = p2; p2 = t; }
            if (p1 < p0) { unsigned long long t = p0; p0 = p1; p1 = t; }
        }
    }
    unsigned long long wmin[3];
    unsigned long long h = p0;
#pragma unroll
    for (int r = 0; r < 3; ++r) {
        unsigned long long w = h;
#pragma unroll
        for (int s = 1; s < 64; s <<= 1) {
            unsigned long long o = __shfl_xor(w, s, 64);
            w = (o < w) ? o : w;
        }
        wmin[r] = w;
        if (h == w) { p0 = p1; p1 = p2; p2 = ~0ULL; h = p0; }
    }
    if (lane == 0) {
        float d0 = __uint_as_float((unsigned)(wmin[0] >> 32));
        float d1 = __uint_as_float((unsigned)(wmin[1] >> 32));
        float d2 = __uint_as_float((unsigned)(wmin[2] >> 32));
        float s0 = sqrtf(fmaxf(d0, 0.f)), s1 = sqrtf(fmaxf(d1, 0.f)), s2 = sqrtf(fmaxf(d2, 0.f));
        float r0 = 1.f/(s0+1e-8f), r1 = 1.f/(s1+1e-8f), r2 = 1.f/(s2+1e-8f);
        float inv = 1.f/(r0+r1+r2);
        idx3[(size_t)q*3+0] = (int)(unsigned)wmin[0];
        idx3[(size_t)q*3+1] = (int)(unsigned)wmin[1];
        idx3[(size_t)q*3+2] = (int)(unsigned)wmin[2];
        w3[(size_t)q*3+0] = r0*inv; w3[(size_t)q*3+1] = r1*inv; w3[(size_t)q*3+2] = r2*inv;
    }
}

// ---------------------------------------------------------------------------
// x[m][c] = relu(bn2(tu_lin2_w @ target_feature)) + three_interpolate(f_t)
extern "C" __global__ __launch_bounds__(256) void k_feat(
    const float* __restrict__ tfeat, const float* __restrict__ w2,
    const float* __restrict__ g, const float* __restrict__ bb,
    const float* __restrict__ f_t, const int* __restrict__ idx3,
    const float* __restrict__ w3, float* __restrict__ x)
{
    __shared__ float4 As4[32 * LDSS], Bs4[32 * LDSS];
    int t = threadIdx.x, tm = t >> 4, tn = t & 15;
    int m0 = blockIdx.x * 128;
    int b = m0 >> 13;
    size_t col0_4 = (size_t)(m0 & (M_ - 1)) >> 2;
    const float4* src4 = (const float4*)tfeat + (size_t)b * C_ * (M_ / 4);
    float acc[8][8] = {};
    for (int k0 = 0; k0 < C_; k0 += 32) {
        stage_direct(As4, src4, M_ / 4, k0, col0_4, t);
        stage_transpose((float*)Bs4, w2, 0, C_, k0, t);
        __syncthreads();
        gemm_step(As4, Bs4, tm, tn, acc);
        __syncthreads();
    }
    int c0 = tn * 8;
    float gc[8], bc[8];
    load8(g + c0, gc); load8(bb + c0, bc);
    const float* fb = f_t + (size_t)b * N_ * C_;
#pragma unroll
    for (int mm = 0; mm < 8; ++mm) {
        int m = m0 + tm * 8 + mm;
        int   i0 = idx3[m*3+0], i1 = idx3[m*3+1], i2 = idx3[m*3+2];
        float u0 = w3[m*3+0],  u1 = w3[m*3+1],  u2 = w3[m*3+2];
        float r0[8], r1[8], r2[8];
        load8(fb + (size_t)i0 * C_ + c0, r0);
        load8(fb + (size_t)i1 * C_ + c0, r1);
        load8(fb + (size_t)i2 * C_ + c0, r2);
        float o[8];
#pragma unroll
        for (int j = 0; j < 8; ++j) {
            float y = fmaxf(fmaf(acc[mm][j], gc[j] * BNINV, bc[j]), 0.f);
            o[j] = y + u0 * r0[j] + u1 * r1[j] + u2 * r2[j];
        }
        store8(x + (size_t)m * C_ + c0, o);
    }
}

// ---------------------------------------------------------------------------
// kNN (wave/query, packed u64 keys) — unchanged from round 1
extern "C" __global__ __launch_bounds__(256) void k_knn(
    const float* __restrict__ txyz, int* __restrict__ out_knn)
{
    int q    = blockIdx.x * 4 + (threadIdx.x >> 6);
    int lane = threadIdx.x & 63;
    int b    = q / M_;
    int m    = q - b * M_;
    const float* base = txyz + (size_t)b * M_ * 3;
    float qx = base[m*3+0], qy = base[m*3+1], qz = base[m*3+2];

    unsigned long long p[K_];
#pragma unroll
    for (int i = 0; i < K_; ++i) p[i] = ~0ULL;

    for (int i = 0; i < M_/64; ++i) {
        int j = lane + (i << 6);
        float dx = base[j*3+0]-qx, dy = base[j*3+1]-qy, dz = base[j*3+2]-qz;
        float d = __fadd_rn(__fadd_rn(__fmul_rn(dx,dx), __fmul_rn(dy,dy)), __fmul_rn(dz,dz));
        unsigned long long key = ((unsigned long long)__float_as_uint(d) << 32) | (unsigned)j;
        if (key < p[K_-1]) {
            p[K_-1] = key;
#pragma unroll
            for (int t = K_-1; t > 0; --t) {
                unsigned long long a = p[t-1], c2 = p[t];
                bool sw = c2 < a;
                p[t-1] = sw ? c2 : a;
                p[t]   = sw ? a  : c2;
            }
        }
    }

    unsigned long long keep = 0;
    unsigned long long h = p[0];
#pragma unroll
    for (int r = 0; r < K_; ++r) {
        unsigned long long w = h;
#pragma unroll
        for (int s = 1; s < 64; s <<= 1) {
            unsigned long long o = __shfl_xor(w, s, 64);
            w = (o < w) ? o : w;
        }
        if (lane == r) keep = w;
        if (h == w) {
#pragma unroll
            for (int t = 0; t < K_-1; ++t) p[t] = p[t+1];
            p[K_-1] = ~0ULL;
            h = p[0];
        }
    }
    if (lane < K_)
        out_knn[(size_t)q*K_ + lane] = (int)(unsigned)keep;
}

// ---------------------------------------------------------------------------
// x1 = relu(bn(x @ W.T))   (A transpose-staged, K=128)
extern "C" __global__ __launch_bounds__(256) void k_lin(
    const float* __restrict__ xin, const float* __restrict__ w,
    const float* __restrict__ g, const float* __restrict__ bb,
    float* __restrict__ xout)
{
    __shared__ float4 As4[32 * LDSS], Bs4[32 * LDSS];
    int t = threadIdx.x, tm = t >> 4, tn = t & 15;
    int m0 = blockIdx.x * 128;
    float acc[8][8] = {};
    for (int k0 = 0; k0 < C_; k0 += 32) {
        stage_transpose((float*)As4, xin, m0, C_, k0, t);
        stage_transpose((float*)Bs4, w, 0, C_, k0, t);
        __syncthreads();
        gemm_step(As4, Bs4, tm, tn, acc);
        __syncthreads();
    }
    int c0 = tn * 8;
    float gc[8], bc[8];
    load8(g + c0, gc); load8(bb + c0, bc);
#pragma unroll
    for (int mm = 0; mm < 8; ++mm) {
        int m = m0 + tm * 8 + mm;
        float o[8];
#pragma unroll
        for (int j = 0; j < 8; ++j)
            o[j] = fmaxf(fmaf(acc[mm][j], gc[j] * BNINV, bc[j]), 0.f);
        store8(xout + (size_t)m * C_ + c0, o);
    }
}

// ---------------------------------------------------------------------------
// q/k/v = x1 @ W.T + bias     (blockIdx.y selects matrix)
extern "C" __global__ __launch_bounds__(256) void k_qkv(
    const float* __restrict__ x1,
    const float* __restrict__ wq, const float* __restrict__ bq,
    const float* __restrict__ wk, const float* __restrict__ bk,
    const float* __restrict__ wv, const float* __restrict__ bv,
    float* __restrict__ q, float* __restrict__ k, float* __restrict__ v)
{
    __shared__ float4 As4[32 * LDSS], Bs4[32 * LDSS];
    int t = threadIdx.x, tm = t >> 4, tn = t & 15;
    int m0 = blockIdx.x * 128;
    int which = blockIdx.y;
    const float* W  = (which == 0) ? wq : (which == 1) ? wk : wv;
    const float* bi = (which == 0) ? bq : (which == 1) ? bk : bv;
    float*       out= (which == 0) ? q  : (which == 1) ? k  : v;
    float acc[8][8] = {};
    for (int k0 = 0; k0 < C_; k0 += 32) {
        stage_transpose((float*)As4, x1, m0, C_, k0, t);
        stage_transpose((float*)Bs4, W, 0, C_, k0, t);
        __syncthreads();
        gemm_step(As4, Bs4, tm, tn, acc);
        __syncthreads();
    }
    int c0 = tn * 8;
    float bc[8];
    load8(bi + c0, bc);
#pragma unroll
    for (int mm = 0; mm < 8; ++mm) {
        int m = m0 + tm * 8 + mm;
        float o[8];
#pragma unroll
        for (int j = 0; j < 8; ++j) o[j] = acc[mm][j] + bc[j];
        store8(out + (size_t)m * C_ + c0, o);
    }
}

// ---------------------------------------------------------------------------
// Attention core (5-phase): gathers + pr MLP + w MLP + softmax + agg + bn2.
// Writes x2 row-major. One block (128 thr) per point.
extern "C" __global__ __launch_bounds__(128) void k_attn2(
    const float* __restrict__ q, const float* __restrict__ kf, const float* __restrict__ vf,
    const int* __restrict__ knn, const float* __restrict__ txyz,
    const float* __restrict__ p1w, const float* __restrict__ p1b,
    const float* __restrict__ pbg, const float* __restrict__ pbb,
    const float* __restrict__ p2w, const float* __restrict__ p2b,
    const float* __restrict__ wb1g, const float* __restrict__ wb1b,
    const float* __restrict__ wl1, const float* __restrict__ wl1b,
    const float* __restrict__ wb2g, const float* __restrict__ wb2b,
    const float* __restrict__ wl2, const float* __restrict__ wl2b,
    const float* __restrict__ bn2g, const float* __restrict__ bn2b,
    float* __restrict__ x2out)
{
    __shared__ float tshs[K_ * C_];     // [nb][c]
    __shared__ float svs [K_ * C_];     // [nb][c]
    __shared__ float wl1s[CS_ * 132];   // [s][c], padded
    __shared__ float wl2s[CS_ * 17];    // [cs][j], padded
    __shared__ float ashs[K_ * 17];     // [nb][s], padded
    __shared__ float wshs[K_ * 17];     // [nb][cs], padded

    int bm = blockIdx.x;
    int b  = bm >> 13;
    int c  = threadIdx.x;

    // stage wl1 (16x128) and wl2 (16x16)
#pragma unroll
    for (int i = 0; i < 16; ++i) {
        int idx = c + i * 128;
        wl1s[(idx >> 7) * 132 + (idx & 127)] = wl1[idx];
    }
    {
        int i1 = c, i2 = c + 128;
        if (i1 < 256) wl2s[(i1 >> 4) * 17 + (i1 & 15)] = wl2[i1];
        if (i2 < 256) wl2s[(i2 >> 4) * 17 + (i2 & 15)] = wl2[i2];
    }

    float qc = q[(size_t)bm * C_ + c];
    float qx = txyz[(size_t)bm*3+0], qy = txyz[(size_t)bm*3+1], qz = txyz[(size_t)bm*3+2];
    float p2w0 = p2w[c*3+0], p2w1 = p2w[c*3+1], p2w2 = p2w[c*3+2], p2bc = p2b[c];
    float b1s = wb1g[c]*BNINV, b1b = wb1b[c];
    float a00=p1w[0],a01=p1w[1],a02=p1w[2],a10=p1w[3],a11=p1w[4],a12=p1w[5],a20=p1w[6],a21=p1w[7],a22=p1w[8];
    float pb0=p1b[0], pb1=p1b[1], pb2=p1b[2];
    float g0=pbg[0]*BNINV, g1=pbg[1]*BNINV, g2=pbg[2]*BNINV;
    float hb0=pbb[0], hb1=pbb[1], hb2=pbb[2];
    const float* txb = txyz + (size_t)b * M_ * 3;

    __syncthreads();   // staging done

    // phase 1: per-neighbor pr, tsh, sv
    for (int t = 0; t < K_; ++t) {
        int nb = knn[(size_t)bm*K_ + t];
        float dx = txb[nb*3+0]-qx, dy = txb[nb*3+1]-qy, dz = txb[nb*3+2]-qz;
        float h0 = fmaxf(fmaf(fmaf(a02,dz, fmaf(a01,dy, fmaf(a00,dx, pb0))), g0, hb0), 0.f);
        float h1 = fmaxf(fmaf(fmaf(a12,dz, fmaf(a11,dy, fmaf(a10,dx, pb1))), g1, hb1), 0.f);
        float h2 = fmaxf(fmaf(fmaf(a22,dz, fmaf(a21,dy, fmaf(a20,dx, pb2))), g2, hb2), 0.f);
        float pr = fmaf(p2w2,h2, fmaf(p2w1,h1, fmaf(p2w0,h0, p2bc)));
        size_t nrow = ((size_t)b*M_ + nb)*C_ + c;
        float r = kf[nrow] - qc + pr;
        tshs[t*C_ + c] = fmaxf(fmaf(r, b1s, b1b), 0.f);
        svs [t*C_ + c] = vf[nrow] + pr;
    }
    __syncthreads();

    // phase 2: 16x128 matvec for all neighbors; thread = (s = c>>3, u = c&7)
    {
        int s = c >> 3, u = c & 7;
        float w1b = wl1b[s], gg = wb2g[s]*BNINV, gb = wb2b[s];
        for (int nb = 0; nb < K_; ++nb) {
            float a = 0.f;
#pragma unroll
            for (int i = 0; i < 16; ++i)
                a = fmaf(wl1s[s*132 + u + 8*i], tshs[nb*C_ + u + 8*i], a);
            a += __shfl_down(a, 4, 8);
            a += __shfl_down(a, 2, 8);
            a += __shfl_down(a, 1, 8);
            if (u == 0)
                ashs[nb*17 + s] = fmaxf(fmaf(a + w1b, gg, gb), 0.f);
        }
    }
    __syncthreads();

    // phase 3: 16x16 matvec; thread covers (nb = c>>3, cs = c&7 and +8)
    {
        int nb = c >> 3;
        int cs1 = c & 7, cs2 = (c & 7) + 8;
        float a1 = wl2b[cs1], a2 = wl2b[cs2];
#pragma unroll
        for (int j = 0; j < CS_; ++j) {
            float av = ashs[nb*17 + j];
            a1 = fmaf(wl2s[cs1*17 + j], av, a1);
            a2 = fmaf(wl2s[cs2*17 + j], av, a2);
        }
        wshs[nb*17 + cs1] = a1;
        wshs[nb*17 + cs2] = a2;
    }
    __syncthreads();

    // phase 4: softmax over nb per cs
    if (c < CS_) {
        float mx = -3e38f;
#pragma unroll
        for (int nb = 0; nb < K_; ++nb) mx = fmaxf(mx, wshs[nb*17 + c]);
        float ssum = 0.f;
#pragma unroll
        for (int nb = 0; nb < K_; ++nb) {
            float e = __expf(wshs[nb*17 + c] - mx);
            wshs[nb*17 + c] = e; ssum += e;
        }
        float inv = 1.f / ssum;
#pragma unroll
        for (int nb = 0; nb < K_; ++nb) wshs[nb*17 + c] *= inv;
    }
    __syncthreads();

    // phase 5: weighted aggregation + bn2 + relu
    float agg = 0.f;
    int cs = c & (CS_ - 1);
#pragma unroll
    for (int nb = 0; nb < K_; ++nb)
        agg = fmaf(svs[nb*C_ + c], wshs[nb*17 + cs], agg);
    float x2 = fmaxf(fmaf(agg, bn2g[c]*BNINV, bn2b[c]), 0.f);
    x2out[(size_t)bm * C_ + c] = x2;
}

// ---------------------------------------------------------------------------
// out[b][c][m] = relu(bn3(x2 @ l3w.T) + identity)   (transposed store)
extern "C" __global__ __launch_bounds__(256) void k_lin3(
    const float* __restrict__ x2, const float* __restrict__ w,
    const float* __restrict__ g, const float* __restrict__ bb,
    const float* __restrict__ xid, float* __restrict__ out)
{
    __shared__ float4 As4[32 * LDSS], Bs4[32 * LDSS];
    int t = threadIdx.x, tm = t >> 4, tn = t & 15;
    int m0 = blockIdx.x * 128;
    int b  = m0 >> 13;
    float acc[8][8] = {};
    for (int k0 = 0; k0 < C_; k0 += 32) {
        stage_transpose((float*)As4, x2, m0, C_, k0, t);
        stage_transpose((float*)Bs4, w, 0, C_, k0, t);
        __syncthreads();
        gemm_step(As4, Bs4, tm, tn, acc);
        __syncthreads();
    }
    int c0 = tn * 8;
    float gc[8], bc[8];
    load8(g + c0, gc); load8(bb + c0, bc);
#pragma unroll
    for (int mm = 0; mm < 8; ++mm) {
        int m = m0 + tm * 8 + mm;
        float idv[8];
        load8(xid + (size_t)m * C_ + c0, idv);
#pragma unroll
        for (int j = 0; j < 8; ++j) {
            float x3 = fmaf(acc[mm][j], gc[j] * BNINV, bc[j]);
            acc[mm][j] = fmaxf(x3 + idv[j], 0.f);
        }
    }
    int mloc = (m0 & (M_ - 1)) + tm * 8;
    float* ob = out + (size_t)b * C_ * M_;
#pragma unroll
    for (int j = 0; j < 8; ++j) {
        float* p = ob + (size_t)(c0 + j) * M_ + mloc;
        *(float4*)p       = make_float4(acc[0][j], acc[1][j], acc[2][j], acc[3][j]);
        *(float4*)(p + 4) = make_float4(acc[4][j], acc[5][j], acc[6][j], acc[7][j]);
    }
}

// ---------------------------------------------------------------------------
extern "C" void kernel_launch(void* const* d_in, const int* in_sizes, int n_in,
                              void* d_out, int out_size, void* d_ws, size_t ws_size,
                              hipStream_t stream)
{
    const float* xyz   = (const float*)d_in[0];
    const float* feat  = (const float*)d_in[1];
    const float* txyz  = (const float*)d_in[2];
    const float* tfeat = (const float*)d_in[3];
    const float* tu1w  = (const float*)d_in[4];
    const float* tu1g  = (const float*)d_in[5];
    const float* tu1b  = (const float*)d_in[6];
    const float* tu2w  = (const float*)d_in[7];
    const float* tu2g  = (const float*)d_in[8];
    const float* tu2b  = (const float*)d_in[9];
    const float* bl1w  = (const float*)d_in[10];
    const float* bl1g  = (const float*)d_in[11];
    const float* bl1b  = (const float*)d_in[12];
    const float* wq    = (const float*)d_in[13];
    const float* bq    = (const float*)d_in[14];
    const float* wk    = (const float*)d_in[15];
    const float* bk    = (const float*)d_in[16];
    const float* wv    = (const float*)d_in[17];
    const float* bv    = (const float*)d_in[18];
    const float* p1w   = (const float*)d_in[19];
    const float* p1b   = (const float*)d_in[20];
    const float* pbg   = (const float*)d_in[21];
    const float* pbb   = (const float*)d_in[22];
    const float* p2w   = (const float*)d_in[23];
    const float* p2b   = (const float*)d_in[24];
    const float* wb1g  = (const float*)d_in[25];
    const float* wb1b  = (const float*)d_in[26];
    const float* wl1   = (const float*)d_in[27];
    const float* wl1b  = (const float*)d_in[28];
    const float* wb2g  = (const float*)d_in[29];
    const float* wb2b  = (const float*)d_in[30];
    const float* wl2   = (const float*)d_in[31];
    const float* wl2b  = (const float*)d_in[32];
    const float* bn2g  = (const float*)d_in[33];
    const float* bn2b  = (const float*)d_in[34];
    const float* l3w   = (const float*)d_in[35];
    const float* bn3g  = (const float*)d_in[36];
    const float* bn3b  = (const float*)d_in[37];

    char* ws = (char*)d_ws;
    size_t off = 0;
    auto alloc = [&](size_t bytes) { void* p = ws + off; off += (bytes + 255) & ~(size_t)255; return p; };
    float* f_t  = (float*)alloc(sizeof(float) * B_ * N_ * C_);
    int*   idx3 = (int*)  alloc(sizeof(int)   * B_ * M_ * 3);
    float* w3   = (float*)alloc(sizeof(float) * B_ * M_ * 3);
    float* x    = (float*)alloc(sizeof(float) * B_ * M_ * C_);
    float* x1   = (float*)alloc(sizeof(float) * B_ * M_ * C_);
    float* qb   = (float*)alloc(sizeof(float) * B_ * M_ * C_);
    float* kb   = (float*)alloc(sizeof(float) * B_ * M_ * C_);
    float* vb   = (float*)alloc(sizeof(float) * B_ * M_ * C_);
    int*   knn  = (int*)  alloc(sizeof(int)   * B_ * M_ * K_);
    float* x2   = x1;    // x1 is dead after k_qkv; reuse as x2

    k_f       <<<B_*N_/128,       256, 0, stream>>>(feat, tu1w, tu1g, tu1b, f_t);
    k_three_nn<<<B_*M_/4,         256, 0, stream>>>(xyz, txyz, idx3, w3);
    k_feat    <<<B_*M_/128,       256, 0, stream>>>(tfeat, tu2w, tu2g, tu2b, f_t, idx3, w3, x);
    k_knn     <<<B_*M_/4,         256, 0, stream>>>(txyz, knn);
    k_lin     <<<B_*M_/128,       256, 0, stream>>>(x, bl1w, bl1g, bl1b, x1);
    k_qkv     <<<dim3(B_*M_/128,3),256, 0, stream>>>(x1, wq, bq, wk, bk, wv, bv, qb, kb, vb);
    k_attn2   <<<B_*M_,           128, 0, stream>>>(qb, kb, vb, knn, txyz,
                                                    p1w, p1b, pbg, pbb, p2w, p2b,
                                                    wb1g, wb1b, wl1, wl1b, wb2g, wb2b, wl2, wl2b,
                                                    bn2g, bn2b, x2);
    k_lin3    <<<B_*M_/128,       256, 0, stream>>>(x2, l3w, bn3g, bn3b, x, (float*)d_out);
}

// Round 7
// 445.707 us; speedup vs baseline: 5.1471x; 1.5236x over previous
//
#include <hip/hip_runtime.h>
#include <cstddef>
#include <cstdint>

#define B_  2
#define N_  2048
#define M_  8192
#define C1_ 256
#define C_  128
#define K_  16
#define CS_ 16

// 1/sqrt(1+1e-5)
#define BNINV 0.9999950000374997f

// ======================= tiled fp32 GEMM machinery =========================
// BM=BN=128, BK=32, 256 threads, 8x8 micro-tile per thread.
// LDS tiles stored [BK][BM(+pad)] as float4 with row stride 33 float4 (132 f).
#define LDSS 33   // float4 stride per k-row

__device__ __forceinline__ void stage_direct(float4* Ls4, const float4* src4,
                                             size_t row_stride4, int k0,
                                             size_t col0_4, int t)
{
#pragma unroll
    for (int i = 0; i < 4; ++i) {
        int idx = t + i * 256;          // 0..1023
        int kk = idx >> 5, f4 = idx & 31;
        Ls4[kk * LDSS + f4] = src4[(size_t)(k0 + kk) * row_stride4 + col0_4 + f4];
    }
}

// src row-major [rows][ldk]; stage 128 rows starting at row0, k-range [k0,k0+32)
__device__ __forceinline__ void stage_transpose(float* Lsf, const float* src,
                                                int row0, int ldk, int k0, int t)
{
    int u = t & 7, r = t >> 3;          // u: k-quad, r: 0..31
#pragma unroll
    for (int i = 0; i < 4; ++i) {
        int row = r + i * 32;
        float4 v = *(const float4*)(src + (size_t)(row0 + row) * ldk + k0 + u * 4);
        Lsf[(u * 4 + 0) * 132 + row] = v.x;
        Lsf[(u * 4 + 1) * 132 + row] = v.y;
        Lsf[(u * 4 + 2) * 132 + row] = v.z;
        Lsf[(u * 4 + 3) * 132 + row] = v.w;
    }
}

__device__ __forceinline__ void gemm_step(const float4* As4, const float4* Bs4,
                                          int tm, int tn, float acc[8][8])
{
#pragma unroll 4
    for (int kk = 0; kk < 32; ++kk) {
        float4 a0 = As4[kk * LDSS + tm * 2];
        float4 a1 = As4[kk * LDSS + tm * 2 + 1];
        float4 b0 = Bs4[kk * LDSS + tn * 2];
        float4 b1 = Bs4[kk * LDSS + tn * 2 + 1];
        float av[8] = {a0.x,a0.y,a0.z,a0.w,a1.x,a1.y,a1.z,a1.w};
        float bv[8] = {b0.x,b0.y,b0.z,b0.w,b1.x,b1.y,b1.z,b1.w};
#pragma unroll
        for (int i = 0; i < 8; ++i)
#pragma unroll
            for (int j = 0; j < 8; ++j)
                acc[i][j] = fmaf(av[i], bv[j], acc[i][j]);
    }
}

__device__ __forceinline__ void load8(const float* p, float* v)
{
    float4 a = *(const float4*)p, b = *(const float4*)(p + 4);
    v[0]=a.x; v[1]=a.y; v[2]=a.z; v[3]=a.w; v[4]=b.x; v[5]=b.y; v[6]=b.z; v[7]=b.w;
}
__device__ __forceinline__ void store8(float* p, const float* v)
{
    *(float4*)p       = make_float4(v[0],v[1],v[2],v[3]);
    *(float4*)(p + 4) = make_float4(v[4],v[5],v[6],v[7]);
}

// ---------------------------------------------------------------------------
// f_t[bn][c] = relu(bn1(sum_j W1[c][j] * F[b][j][n]))   (A direct, K=256)
extern "C" __global__ __launch_bounds__(256) void k_f(
    const float* __restrict__ feature, const float* __restrict__ w,
    const float* __restrict__ g, const float* __restrict__ bb,
    float* __restrict__ f_t)
{
    __shared__ float4 As4[32 * LDSS], Bs4[32 * LDSS];
    int t = threadIdx.x, tm = t >> 4, tn = t & 15;
    int m0 = blockIdx.x * 128;
    int b = m0 >> 11;
    size_t col0_4 = (size_t)(m0 & (N_ - 1)) >> 2;
    const float4* src4 = (const float4*)feature + (size_t)b * C1_ * (N_ / 4);
    float acc[8][8] = {};
    for (int k0 = 0; k0 < C1_; k0 += 32) {
        stage_direct(As4, src4, N_ / 4, k0, col0_4, t);
        stage_transpose((float*)Bs4, w, 0, C1_, k0, t);
        __syncthreads();
        gemm_step(As4, Bs4, tm, tn, acc);
        __syncthreads();
    }
    int c0 = tn * 8;
    float gc[8], bc[8];
    load8(g + c0, gc); load8(bb + c0, bc);
#pragma unroll
    for (int mm = 0; mm < 8; ++mm) {
        int m = m0 + tm * 8 + mm;
        float o[8];
#pragma unroll
        for (int j = 0; j < 8; ++j)
            o[j] = fmaxf(fmaf(acc[mm][j], gc[j] * BNINV, bc[j]), 0.f);
        store8(f_t + (size_t)m * C_ + c0, o);
    }
}

// ---------------------------------------------------------------------------
// three_nn (wave/query, packed u64 keys) — unchanged
extern "C" __global__ __launch_bounds__(256) void k_three_nn(
    const float* __restrict__ xyz, const float* __restrict__ txyz,
    int* __restrict__ idx3, float* __restrict__ w3)
{
    int q    = blockIdx.x * 4 + (threadIdx.x >> 6);
    int lane = threadIdx.x & 63;
    int b    = q / M_;
    const float* src = xyz + (size_t)b * N_ * 3;
    float qx = txyz[(size_t)q*3+0], qy = txyz[(size_t)q*3+1], qz = txyz[(size_t)q*3+2];

    unsigned long long p0 = ~0ULL, p1 = ~0ULL, p2 = ~0ULL;
    for (int i = 0; i < N_/64; ++i) {
        int j = lane + (i << 6);
        float dx = src[j*3+0]-qx, dy = src[j*3+1]-qy, dz = src[j*3+2]-qz;
        float d = __fadd_rn(__fadd_rn(__fmul_rn(dx,dx), __fmul_rn(dy,dy)), __fmul_rn(dz,dz));
        unsigned long long key = ((unsigned long long)__float_as_uint(d) << 32) | (unsigned)j;
        if (key < p2) {
            p2 = key;
            if (p2 < p1) { unsigned long long t = p1; p1 = p2; p2 = t; }
            if (p1 < p0) { unsigned long long t = p0; p0 = p1; p1 = t; }
        }
    }
    unsigned long long wmin[3];
    unsigned long long h = p0;
#pragma unroll
    for (int r = 0; r < 3; ++r) {
        unsigned long long w = h;
#pragma unroll
        for (int s = 1; s < 64; s <<= 1) {
            unsigned long long o = __shfl_xor(w, s, 64);
            w = (o < w) ? o : w;
        }
        wmin[r] = w;
        if (h == w) { p0 = p1; p1 = p2; p2 = ~0ULL; h = p0; }
    }
    if (lane == 0) {
        float d0 = __uint_as_float((unsigned)(wmin[0] >> 32));
        float d1 = __uint_as_float((unsigned)(wmin[1] >> 32));
        float d2 = __uint_as_float((unsigned)(wmin[2] >> 32));
        float s0 = sqrtf(fmaxf(d0, 0.f)), s1 = sqrtf(fmaxf(d1, 0.f)), s2 = sqrtf(fmaxf(d2, 0.f));
        float r0 = 1.f/(s0+1e-8f), r1 = 1.f/(s1+1e-8f), r2 = 1.f/(s2+1e-8f);
        float inv = 1.f/(r0+r1+r2);
        idx3[(size_t)q*3+0] = (int)(unsigned)wmin[0];
        idx3[(size_t)q*3+1] = (int)(unsigned)wmin[1];
        idx3[(size_t)q*3+2] = (int)(unsigned)wmin[2];
        w3[(size_t)q*3+0] = r0*inv; w3[(size_t)q*3+1] = r1*inv; w3[(size_t)q*3+2] = r2*inv;
    }
}

// ---------------------------------------------------------------------------
// x[m][c] = relu(bn2(tu_lin2_w @ target_feature)) + three_interpolate(f_t)
extern "C" __global__ __launch_bounds__(256) void k_feat(
    const float* __restrict__ tfeat, const float* __restrict__ w2,
    const float* __restrict__ g, const float* __restrict__ bb,
    const float* __restrict__ f_t, const int* __restrict__ idx3,
    const float* __restrict__ w3, float* __restrict__ x)
{
    __shared__ float4 As4[32 * LDSS], Bs4[32 * LDSS];
    int t = threadIdx.x, tm = t >> 4, tn = t & 15;
    int m0 = blockIdx.x * 128;
    int b = m0 >> 13;
    size_t col0_4 = (size_t)(m0 & (M_ - 1)) >> 2;
    const float4* src4 = (const float4*)tfeat + (size_t)b * C_ * (M_ / 4);
    float acc[8][8] = {};
    for (int k0 = 0; k0 < C_; k0 += 32) {
        stage_direct(As4, src4, M_ / 4, k0, col0_4, t);
        stage_transpose((float*)Bs4, w2, 0, C_, k0, t);
        __syncthreads();
        gemm_step(As4, Bs4, tm, tn, acc);
        __syncthreads();
    }
    int c0 = tn * 8;
    float gc[8], bc[8];
    load8(g + c0, gc); load8(bb + c0, bc);
    const float* fb = f_t + (size_t)b * N_ * C_;
#pragma unroll
    for (int mm = 0; mm < 8; ++mm) {
        int m = m0 + tm * 8 + mm;
        int   i0 = idx3[m*3+0], i1 = idx3[m*3+1], i2 = idx3[m*3+2];
        float u0 = w3[m*3+0],  u1 = w3[m*3+1],  u2 = w3[m*3+2];
        float r0[8], r1[8], r2[8];
        load8(fb + (size_t)i0 * C_ + c0, r0);
        load8(fb + (size_t)i1 * C_ + c0, r1);
        load8(fb + (size_t)i2 * C_ + c0, r2);
        float o[8];
#pragma unroll
        for (int j = 0; j < 8; ++j) {
            float y = fmaxf(fmaf(acc[mm][j], gc[j] * BNINV, bc[j]), 0.f);
            o[j] = y + u0 * r0[j] + u1 * r1[j] + u2 * r2[j];
        }
        store8(x + (size_t)m * C_ + c0, o);
    }
}

// ---------------------------------------------------------------------------
// kNN: one wave per query. Wave-distributed sorted top-16 (lane r holds the
// r-th smallest packed u64 key) + shared threshold tau = list[15]. Per
// candidate: 1 u64 compare + ballot. Accepted candidates (expected ~140 per
// query total) merge via uniform-control ffs loop: broadcast key, re-check
// vs updated tau, position = popcount(ballot(list<key)), shfl_up shift-insert.
// Exact (d,idx) lexicographic order == lax.top_k tie-break.
extern "C" __global__ __launch_bounds__(256) void k_knn(
    const float* __restrict__ txyz, int* __restrict__ out_knn)
{
    int q    = blockIdx.x * 4 + (threadIdx.x >> 6);
    int lane = threadIdx.x & 63;
    int b    = q / M_;
    int m    = q - b * M_;
    const float* base = txyz + (size_t)b * M_ * 3;
    float qx = base[m*3+0], qy = base[m*3+1], qz = base[m*3+2];

    unsigned long long list = ~0ULL;   // lanes 0..15: ascending global top-16
    unsigned long long tau  = ~0ULL;   // uniform copy of list[15]

    for (int i = 0; i < M_/64; ++i) {
        int j = lane + (i << 6);
        float dx = base[j*3+0]-qx, dy = base[j*3+1]-qy, dz = base[j*3+2]-qz;
        float d = __fadd_rn(__fadd_rn(__fmul_rn(dx,dx), __fmul_rn(dy,dy)), __fmul_rn(dz,dz));
        unsigned long long key = ((unsigned long long)__float_as_uint(d) << 32) | (unsigned)j;
        unsigned long long mask = __ballot(key < tau);
        while (mask) {
            int src = (int)__ffsll((long long)mask) - 1;   // uniform
            mask &= mask - 1;
            unsigned long long kk = __shfl(key, src, 64);  // uniform broadcast
            if (kk >= tau) continue;                        // re-check (uniform)
            unsigned long long below = __ballot(list < kk) & 0xFFFFull;
            int pos = __popcll(below);                      // uniform, <= 15
            unsigned long long sh = __shfl_up(list, 1, 64);
            if (lane == pos)                    list = kk;
            else if (lane > pos && lane < K_)   list = sh;
            tau = __shfl(list, K_ - 1, 64);
        }
    }
    if (lane < K_)
        out_knn[(size_t)q*K_ + lane] = (int)(unsigned)list;
}

// ---------------------------------------------------------------------------
// x1 = relu(bn(x @ W.T))   (A transpose-staged, K=128)
extern "C" __global__ __launch_bounds__(256) void k_lin(
    const float* __restrict__ xin, const float* __restrict__ w,
    const float* __restrict__ g, const float* __restrict__ bb,
    float* __restrict__ xout)
{
    __shared__ float4 As4[32 * LDSS], Bs4[32 * LDSS];
    int t = threadIdx.x, tm = t >> 4, tn = t & 15;
    int m0 = blockIdx.x * 128;
    float acc[8][8] = {};
    for (int k0 = 0; k0 < C_; k0 += 32) {
        stage_transpose((float*)As4, xin, m0, C_, k0, t);
        stage_transpose((float*)Bs4, w, 0, C_, k0, t);
        __syncthreads();
        gemm_step(As4, Bs4, tm, tn, acc);
        __syncthreads();
    }
    int c0 = tn * 8;
    float gc[8], bc[8];
    load8(g + c0, gc); load8(bb + c0, bc);
#pragma unroll
    for (int mm = 0; mm < 8; ++mm) {
        int m = m0 + tm * 8 + mm;
        float o[8];
#pragma unroll
        for (int j = 0; j < 8; ++j)
            o[j] = fmaxf(fmaf(acc[mm][j], gc[j] * BNINV, bc[j]), 0.f);
        store8(xout + (size_t)m * C_ + c0, o);
    }
}

// ---------------------------------------------------------------------------
// q/k/v = x1 @ W.T + bias     (blockIdx.y selects matrix)
extern "C" __global__ __launch_bounds__(256) void k_qkv(
    const float* __restrict__ x1,
    const float* __restrict__ wq, const float* __restrict__ bq,
    const float* __restrict__ wk, const float* __restrict__ bk,
    const float* __restrict__ wv, const float* __restrict__ bv,
    float* __restrict__ q, float* __restrict__ k, float* __restrict__ v)
{
    __shared__ float4 As4[32 * LDSS], Bs4[32 * LDSS];
    int t = threadIdx.x, tm = t >> 4, tn = t & 15;
    int m0 = blockIdx.x * 128;
    int which = blockIdx.y;
    const float* W  = (which == 0) ? wq : (which == 1) ? wk : wv;
    const float* bi = (which == 0) ? bq : (which == 1) ? bk : bv;
    float*       out= (which == 0) ? q  : (which == 1) ? k  : v;
    float acc[8][8] = {};
    for (int k0 = 0; k0 < C_; k0 += 32) {
        stage_transpose((float*)As4, x1, m0, C_, k0, t);
        stage_transpose((float*)Bs4, W, 0, C_, k0, t);
        __syncthreads();
        gemm_step(As4, Bs4, tm, tn, acc);
        __syncthreads();
    }
    int c0 = tn * 8;
    float bc[8];
    load8(bi + c0, bc);
#pragma unroll
    for (int mm = 0; mm < 8; ++mm) {
        int m = m0 + tm * 8 + mm;
        float o[8];
#pragma unroll
        for (int j = 0; j < 8; ++j) o[j] = acc[mm][j] + bc[j];
        store8(out + (size_t)m * C_ + c0, o);
    }
}

// ---------------------------------------------------------------------------
// Attention core (5-phase): gathers + pr MLP + w MLP + softmax + agg + bn2.
// Writes x2 row-major. One block (128 thr) per point.
extern "C" __global__ __launch_bounds__(128) void k_attn2(
    const float* __restrict__ q, const float* __restrict__ kf, const float* __restrict__ vf,
    const int* __restrict__ knn, const float* __restrict__ txyz,
    const float* __restrict__ p1w, const float* __restrict__ p1b,
    const float* __restrict__ pbg, const float* __restrict__ pbb,
    const float* __restrict__ p2w, const float* __restrict__ p2b,
    const float* __restrict__ wb1g, const float* __restrict__ wb1b,
    const float* __restrict__ wl1, const float* __restrict__ wl1b,
    const float* __restrict__ wb2g, const float* __restrict__ wb2b,
    const float* __restrict__ wl2, const float* __restrict__ wl2b,
    const float* __restrict__ bn2g, const float* __restrict__ bn2b,
    float* __restrict__ x2out)
{
    __shared__ float tshs[K_ * C_];     // [nb][c]
    __shared__ float svs [K_ * C_];     // [nb][c]
    __shared__ float wl1s[CS_ * 132];   // [s][c], padded
    __shared__ float wl2s[CS_ * 17];    // [cs][j], padded
    __shared__ float ashs[K_ * 17];     // [nb][s], padded
    __shared__ float wshs[K_ * 17];     // [nb][cs], padded

    int bm = blockIdx.x;
    int b  = bm >> 13;
    int c  = threadIdx.x;

    // stage wl1 (16x128) and wl2 (16x16)
#pragma unroll
    for (int i = 0; i < 16; ++i) {
        int idx = c + i * 128;
        wl1s[(idx >> 7) * 132 + (idx & 127)] = wl1[idx];
    }
    {
        int i1 = c, i2 = c + 128;
        if (i1 < 256) wl2s[(i1 >> 4) * 17 + (i1 & 15)] = wl2[i1];
        if (i2 < 256) wl2s[(i2 >> 4) * 17 + (i2 & 15)] = wl2[i2];
    }

    float qc = q[(size_t)bm * C_ + c];
    float qx = txyz[(size_t)bm*3+0], qy = txyz[(size_t)bm*3+1], qz = txyz[(size_t)bm*3+2];
    float p2w0 = p2w[c*3+0], p2w1 = p2w[c*3+1], p2w2 = p2w[c*3+2], p2bc = p2b[c];
    float b1s = wb1g[c]*BNINV, b1b = wb1b[c];
    float a00=p1w[0],a01=p1w[1],a02=p1w[2],a10=p1w[3],a11=p1w[4],a12=p1w[5],a20=p1w[6],a21=p1w[7],a22=p1w[8];
    float pb0=p1b[0], pb1=p1b[1], pb2=p1b[2];
    float g0=pbg[0]*BNINV, g1=pbg[1]*BNINV, g2=pbg[2]*BNINV;
    float hb0=pbb[0], hb1=pbb[1], hb2=pbb[2];
    const float* txb = txyz + (size_t)b * M_ * 3;

    __syncthreads();   // staging done

    // phase 1: per-neighbor pr, tsh, sv
    for (int t = 0; t < K_; ++t) {
        int nb = knn[(size_t)bm*K_ + t];
        float dx = txb[nb*3+0]-qx, dy = txb[nb*3+1]-qy, dz = txb[nb*3+2]-qz;
        float h0 = fmaxf(fmaf(fmaf(a02,dz, fmaf(a01,dy, fmaf(a00,dx, pb0))), g0, hb0), 0.f);
        float h1 = fmaxf(fmaf(fmaf(a12,dz, fmaf(a11,dy, fmaf(a10,dx, pb1))), g1, hb1), 0.f);
        float h2 = fmaxf(fmaf(fmaf(a22,dz, fmaf(a21,dy, fmaf(a20,dx, pb2))), g2, hb2), 0.f);
        float pr = fmaf(p2w2,h2, fmaf(p2w1,h1, fmaf(p2w0,h0, p2bc)));
        size_t nrow = ((size_t)b*M_ + nb)*C_ + c;
        float r = kf[nrow] - qc + pr;
        tshs[t*C_ + c] = fmaxf(fmaf(r, b1s, b1b), 0.f);
        svs [t*C_ + c] = vf[nrow] + pr;
    }
    __syncthreads();

    // phase 2: 16x128 matvec for all neighbors; thread = (s = c>>3, u = c&7)
    {
        int s = c >> 3, u = c & 7;
        float w1b = wl1b[s], gg = wb2g[s]*BNINV, gb = wb2b[s];
        for (int nb = 0; nb < K_; ++nb) {
            float a = 0.f;
#pragma unroll
            for (int i = 0; i < 16; ++i)
                a = fmaf(wl1s[s*132 + u + 8*i], tshs[nb*C_ + u + 8*i], a);
            a += __shfl_down(a, 4, 8);
            a += __shfl_down(a, 2, 8);
            a += __shfl_down(a, 1, 8);
            if (u == 0)
                ashs[nb*17 + s] = fmaxf(fmaf(a + w1b, gg, gb), 0.f);
        }
    }
    __syncthreads();

    // phase 3: 16x16 matvec; thread covers (nb = c>>3, cs = c&7 and +8)
    {
        int nb = c >> 3;
        int cs1 = c & 7, cs2 = (c & 7) + 8;
        float a1 = wl2b[cs1], a2 = wl2b[cs2];
#pragma unroll
        for (int j = 0; j < CS_; ++j) {
            float av = ashs[nb*17 + j];
            a1 = fmaf(wl2s[cs1*17 + j], av, a1);
            a2 = fmaf(wl2s[cs2*17 + j], av, a2);
        }
        wshs[nb*17 + cs1] = a1;
        wshs[nb*17 + cs2] = a2;
    }
    __syncthreads();

    // phase 4: softmax over nb per cs
    if (c < CS_) {
        float mx = -3e38f;
#pragma unroll
        for (int nb = 0; nb < K_; ++nb) mx = fmaxf(mx, wshs[nb*17 + c]);
        float ssum = 0.f;
#pragma unroll
        for (int nb = 0; nb < K_; ++nb) {
            float e = __expf(wshs[nb*17 + c] - mx);
            wshs[nb*17 + c] = e; ssum += e;
        }
        float inv = 1.f / ssum;
#pragma unroll
        for (int nb = 0; nb < K_; ++nb) wshs[nb*17 + c] *= inv;
    }
    __syncthreads();

    // phase 5: weighted aggregation + bn2 + relu
    float agg = 0.f;
    int cs = c & (CS_ - 1);
#pragma unroll
    for (int nb = 0; nb < K_; ++nb)
        agg = fmaf(svs[nb*C_ + c], wshs[nb*17 + cs], agg);
    float x2 = fmaxf(fmaf(agg, bn2g[c]*BNINV, bn2b[c]), 0.f);
    x2out[(size_t)bm * C_ + c] = x2;
}

// ---------------------------------------------------------------------------
// out[b][c][m] = relu(bn3(x2 @ l3w.T) + identity)   (transposed store)
extern "C" __global__ __launch_bounds__(256) void k_lin3(
    const float* __restrict__ x2, const float* __restrict__ w,
    const float* __restrict__ g, const float* __restrict__ bb,
    const float* __restrict__ xid, float* __restrict__ out)
{
    __shared__ float4 As4[32 * LDSS], Bs4[32 * LDSS];
    int t = threadIdx.x, tm = t >> 4, tn = t & 15;
    int m0 = blockIdx.x * 128;
    int b  = m0 >> 13;
    float acc[8][8] = {};
    for (int k0 = 0; k0 < C_; k0 += 32) {
        stage_transpose((float*)As4, x2, m0, C_, k0, t);
        stage_transpose((float*)Bs4, w, 0, C_, k0, t);
        __syncthreads();
        gemm_step(As4, Bs4, tm, tn, acc);
        __syncthreads();
    }
    int c0 = tn * 8;
    float gc[8], bc[8];
    load8(g + c0, gc); load8(bb + c0, bc);
#pragma unroll
    for (int mm = 0; mm < 8; ++mm) {
        int m = m0 + tm * 8 + mm;
        float idv[8];
        load8(xid + (size_t)m * C_ + c0, idv);
#pragma unroll
        for (int j = 0; j < 8; ++j) {
            float x3 = fmaf(acc[mm][j], gc[j] * BNINV, bc[j]);
            acc[mm][j] = fmaxf(x3 + idv[j], 0.f);
        }
    }
    int mloc = (m0 & (M_ - 1)) + tm * 8;
    float* ob = out + (size_t)b * C_ * M_;
#pragma unroll
    for (int j = 0; j < 8; ++j) {
        float* p = ob + (size_t)(c0 + j) * M_ + mloc;
        *(float4*)p       = make_float4(acc[0][j], acc[1][j], acc[2][j], acc[3][j]);
        *(float4*)(p + 4) = make_float4(acc[4][j], acc[5][j], acc[6][j], acc[7][j]);
    }
}

// ---------------------------------------------------------------------------
extern "C" void kernel_launch(void* const* d_in, const int* in_sizes, int n_in,
                              void* d_out, int out_size, void* d_ws, size_t ws_size,
                              hipStream_t stream)
{
    const float* xyz   = (const float*)d_in[0];
    const float* feat  = (const float*)d_in[1];
    const float* txyz  = (const float*)d_in[2];
    const float* tfeat = (const float*)d_in[3];
    const float* tu1w  = (const float*)d_in[4];
    const float* tu1g  = (const float*)d_in[5];
    const float* tu1b  = (const float*)d_in[6];
    const float* tu2w  = (const float*)d_in[7];
    const float* tu2g  = (const float*)d_in[8];
    const float* tu2b  = (const float*)d_in[9];
    const float* bl1w  = (const float*)d_in[10];
    const float* bl1g  = (const float*)d_in[11];
    const float* bl1b  = (const float*)d_in[12];
    const float* wq    = (const float*)d_in[13];
    const float* bq    = (const float*)d_in[14];
    const float* wk    = (const float*)d_in[15];
    const float* bk    = (const float*)d_in[16];
    const float* wv    = (const float*)d_in[17];
    const float* bv    = (const float*)d_in[18];
    const float* p1w   = (const float*)d_in[19];
    const float* p1b   = (const float*)d_in[20];
    const float* pbg   = (const float*)d_in[21];
    const float* pbb   = (const float*)d_in[22];
    const float* p2w   = (const float*)d_in[23];
    const float* p2b   = (const float*)d_in[24];
    const float* wb1g  = (const float*)d_in[25];
    const float* wb1b  = (const float*)d_in[26];
    const float* wl1   = (const float*)d_in[27];
    const float* wl1b  = (const float*)d_in[28];
    const float* wb2g  = (const float*)d_in[29];
    const float* wb2b  = (const float*)d_in[30];
    const float* wl2   = (const float*)d_in[31];
    const float* wl2b  = (const float*)d_in[32];
    const float* bn2g  = (const float*)d_in[33];
    const float* bn2b  = (const float*)d_in[34];
    const float* l3w   = (const float*)d_in[35];
    const float* bn3g  = (const float*)d_in[36];
    const float* bn3b  = (const float*)d_in[37];

    char* ws = (char*)d_ws;
    size_t off = 0;
    auto alloc = [&](size_t bytes) { void* p = ws + off; off += (bytes + 255) & ~(size_t)255; return p; };
    float* f_t  = (float*)alloc(sizeof(float) * B_ * N_ * C_);
    int*   idx3 = (int*)  alloc(sizeof(int)   * B_ * M_ * 3);
    float* w3   = (float*)alloc(sizeof(float) * B_ * M_ * 3);
    float* x    = (float*)alloc(sizeof(float) * B_ * M_ * C_);
    float* x1   = (float*)alloc(sizeof(float) * B_ * M_ * C_);
    float* qb   = (float*)alloc(sizeof(float) * B_ * M_ * C_);
    float* kb   = (float*)alloc(sizeof(float) * B_ * M_ * C_);
    float* vb   = (float*)alloc(sizeof(float) * B_ * M_ * C_);
    int*   knn  = (int*)  alloc(sizeof(int)   * B_ * M_ * K_);
    float* x2   = x1;    // x1 is dead after k_qkv; reuse as x2

    k_f       <<<B_*N_/128,       256, 0, stream>>>(feat, tu1w, tu1g, tu1b, f_t);
    k_three_nn<<<B_*M_/4,         256, 0, stream>>>(xyz, txyz, idx3, w3);
    k_feat    <<<B_*M_/128,       256, 0, stream>>>(tfeat, tu2w, tu2g, tu2b, f_t, idx3, w3, x);
    k_knn     <<<B_*M_/4,         256, 0, stream>>>(txyz, knn);
    k_lin     <<<B_*M_/128,       256, 0, stream>>>(x, bl1w, bl1g, bl1b, x1);
    k_qkv     <<<dim3(B_*M_/128,3),256, 0, stream>>>(x1, wq, bq, wk, bk, wv, bv, qb, kb, vb);
    k_attn2   <<<B_*M_,           128, 0, stream>>>(qb, kb, vb, knn, txyz,
                                                    p1w, p1b, pbg, pbb, p2w, p2b,
                                                    wb1g, wb1b, wl1, wl1b, wb2g, wb2b, wl2, wl2b,
                                                    bn2g, bn2b, x2);
    k_lin3    <<<B_*M_/128,       256, 0, stream>>>(x2, l3w, bn3g, bn3b, x, (float*)d_out);
}